// Round 2
// baseline (1006.548 us; speedup 1.0000x reference)
//
#include <hip/hip_runtime.h>
#include <hip/hip_bf16.h>

// CrossConv2d via bf16 MFMA implicit GEMM.
// out[n,co,h,w] = relu( BN(conv3x3(xy)) + xy ),  xy = concat(u[b], v[n])
// One block = one (n, 16x16 tile). 512 threads / 8 waves; wave owns 2 rows -> acc[8][2]
// (64 f32/thread, vs 128 in the 256-thread version: +1 wave/SIMD of occupancy).
// MFMA operand swap: A = pixels (M=w), B = weights (N=co) -> D rows are 4 consecutive w
// -> float4 skip-load + float4 store epilogue.
// Staging: double-buffered LDS, T14 async split (issue loads -> MFMA -> cvt+ds_write),
// vectorized float2-pair units with all index math hoisted out of the chunk loop.

#define EPS 1e-5f

typedef __attribute__((ext_vector_type(8))) short short8;   // 8 bf16 = 4 VGPRs
typedef __attribute__((ext_vector_type(4))) float f32x4;
typedef __attribute__((ext_vector_type(2))) float f32x2;

constexpr int C1 = 64, CC = 128, Hd = 128, Wd = 128;
constexpr int HW = Hd * Wd;          // 16384
constexpr int SP = 18;               // halo tile side (16 + 2)
constexpr int ROW = 40;              // ushorts per point: 32 ci + 8 pad (80B, 16B-aligned)
constexpr int WFRAGS = 9 * 4 * 8;    // (t, ci-chunk, co-frag)
constexpr int NTHR = 512;
constexpr int UNITS = 16 * 18 * 10;  // ci-pair x sph x float2-col units per chunk = 2880
constexpr int NU = (UNITS + NTHR - 1) / NTHR;   // 6

// ---- prep: fp32 OIHW weights -> bf16 B-fragments in ws ----
// frag f = (t*4 + c)*8 + cf ; lane l holds 8 bf16: co = cf*16+(l&15), ci = c*32+(l>>4)*8+j
__global__ void prep_weights(const float* __restrict__ wgt, ushort* __restrict__ wf) {
    int idx = blockIdx.x * 256 + threadIdx.x;
    if (idx >= WFRAGS * 64) return;
    int l  = idx & 63;
    int f  = idx >> 6;
    int cf = f & 7;
    int c  = (f >> 3) & 3;
    int t  = f >> 5;
    int kh = t / 3, kw = t % 3;
    int co  = cf * 16 + (l & 15);
    int cib = c * 32 + (l >> 4) * 8;
    ushort* dst = wf + (size_t)idx * 8;
#pragma unroll
    for (int j = 0; j < 8; ++j) {
        float x = wgt[(((size_t)co * CC + cib + j) * 3 + kh) * 3 + kw];
        __hip_bfloat16 bb = __float2bfloat16(x);
        dst[j] = *(ushort*)&bb;
    }
}

// ---- main: one block = one (n, 16x16 tile); 8 waves x 2 rows x 128 co ----
__global__ __launch_bounds__(NTHR, 2)
void crossconv_mfma(const float* __restrict__ u,
                    const float* __restrict__ v,
                    const ushort* __restrict__ wf,
                    const float* __restrict__ gamma,
                    const float* __restrict__ beta,
                    const float* __restrict__ mean,
                    const float* __restrict__ var,
                    float* __restrict__ out) {
    __shared__ alignas(16) ushort in_s[2][SP * SP * ROW];   // 2 x 25920 B
    __shared__ float s_sc[CC], s_sh[CC];

    const int tid = threadIdx.x;
    const int w0 = blockIdx.x * 16;
    const int h0 = blockIdx.y * 16;
    const int n  = blockIdx.z;
    const int b  = n >> 3;
    const float* __restrict__ ubase = u + (size_t)b * C1 * HW;
    const float* __restrict__ vbase = v + (size_t)n * C1 * HW;

    if (tid < CC) {
        float sc = gamma[tid] * rsqrtf(var[tid] + EPS);
        s_sc[tid] = sc;
        s_sh[tid] = beta[tid] - mean[tid] * sc;
    }
    // zero both buffers once: OOB/halo slots are the same every chunk and are
    // never rewritten, so they stay zero for the whole kernel.
    {
        uint4 z{0u, 0u, 0u, 0u};
        uint4* p = (uint4*)&in_s[0][0];
        for (int i = tid; i < 2 * SP * SP * ROW * 2 / 16; i += NTHR) p[i] = z;
    }

    const int l = tid & 63, wid = tid >> 6;     // wave wid owns tile rows 2*wid, 2*wid+1
    const int n16 = l & 15, kgrp = l >> 4;

    // ---- per-unit staging geometry, hoisted out of the chunk loop ----
    // unit e = tid + i*NTHR: cp = ci-pair, sph = halo row, j = float2 column unit
    // covers halo cols spw = {2j-1, 2j}  (image w = gw, gw+1 with gw = w0+2j-2)
    int  goff[NU];
    int  sidx[NU];
    uint lm = 0, m0 = 0, m1 = 0;
#pragma unroll
    for (int i = 0; i < NU; ++i) {
        goff[i] = 0; sidx[i] = ROW;
        int e = tid + i * NTHR;
        if (e < UNITS) {
            int cp  = e / 180;
            int r   = e - cp * 180;
            int sph = r / 10;
            int j   = r - sph * 10;
            int gh  = h0 + sph - 1;
            int gw  = w0 + 2 * j - 2;           // even -> 8B-aligned float2
            sidx[i] = (sph * SP + 2 * j) * ROW + 2 * cp;
            if ((unsigned)gh < (unsigned)Hd && (unsigned)gw < (unsigned)(Wd - 1)) {
                goff[i] = 2 * cp * HW + gh * Wd + gw;
                lm |= 1u << i;
                if (j >= 1) m0 |= 1u << i;      // spw = 2j-1 in tile
                if (j <= 8) m1 |= 1u << i;      // spw = 2j   in tile
            }
        }
    }

    f32x4 acc[8][2];
#pragma unroll
    for (int cf = 0; cf < 8; ++cf) { acc[cf][0] = (f32x4)0.f; acc[cf][1] = (f32x4)0.f; }

    f32x2 sa[NU], sb[NU];          // in-flight staging regs (live across MFMA: T14)

    auto chunk_src = [&](int c) -> const float* {
        return (c < 2) ? ubase + (size_t)c * 32 * HW
                       : vbase + (size_t)(c - 2) * 32 * HW;
    };
    auto stage_load = [&](const float* __restrict__ src) {
#pragma unroll
        for (int i = 0; i < NU; ++i) {
            sa[i] = f32x2{0.f, 0.f}; sb[i] = f32x2{0.f, 0.f};
            if (lm & (1u << i)) {
                const float* p = src + goff[i];
                sa[i] = *(const f32x2*)p;          // ci = 2cp
                sb[i] = *(const f32x2*)(p + HW);   // ci = 2cp+1
            }
        }
    };
    auto stage_write = [&](int buf) {
        ushort* __restrict__ d = in_s[buf];
#pragma unroll
        for (int i = 0; i < NU; ++i) {
            __hip_bfloat16 ax = __float2bfloat16(sa[i].x);
            __hip_bfloat16 bx = __float2bfloat16(sb[i].x);
            __hip_bfloat16 ay = __float2bfloat16(sa[i].y);
            __hip_bfloat16 by = __float2bfloat16(sb[i].y);
            uint v0 = (uint)*(ushort*)&ax | ((uint)*(ushort*)&bx << 16);
            uint v1 = (uint)*(ushort*)&ay | ((uint)*(ushort*)&by << 16);
            if (m0 & (1u << i)) *(uint*)&d[sidx[i] - ROW] = v0;
            if (m1 & (1u << i)) *(uint*)&d[sidx[i]]       = v1;
        }
    };
    // A = pixels (M=w), B = weights (N=co) -> D: col=co, row=w (float4 epilogue)
    auto compute = [&](int buf, int c) {
        const ushort* __restrict__ bs = in_s[buf];
#pragma unroll
        for (int t = 0; t < 9; ++t) {
            const int kh = t / 3, kw = t % 3;
            const int spw = n16 + kw;
            short8 p0 = *(const short8*)&bs[((wid * 2 + 0 + kh) * SP + spw) * ROW + kgrp * 8];
            short8 p1 = *(const short8*)&bs[((wid * 2 + 1 + kh) * SP + spw) * ROW + kgrp * 8];
            const short8* __restrict__ wp =
                (const short8*)wf + ((size_t)(t * 4 + c) * 8) * 64 + l;
#pragma unroll
            for (int cf = 0; cf < 8; ++cf) {
                short8 wfr = wp[(size_t)cf * 64];        // L2-resident, 1KB/wave
                acc[cf][0] = __builtin_amdgcn_mfma_f32_16x16x32_bf16(p0, wfr, acc[cf][0], 0, 0, 0);
                acc[cf][1] = __builtin_amdgcn_mfma_f32_16x16x32_bf16(p1, wfr, acc[cf][1], 0, 0, 0);
            }
        }
    };

    stage_load(chunk_src(0));
    __syncthreads();               // zero-fill + BN table visible
    stage_write(0);
    __syncthreads();

    for (int c = 0; c < 4; ++c) {                  // ci chunks of 32
        if (c < 3) stage_load(chunk_src(c + 1));   // loads fly under MFMA (T14)
        compute(c & 1, c);
        if (c < 3) stage_write((c & 1) ^ 1);
        __syncthreads();           // next buffer ready; current free for c+2
    }

    // ---- epilogue: BN + fp32 skip + ReLU, float4 I/O ----
#pragma unroll
    for (int cf = 0; cf < 8; ++cf) {
        const int co = cf * 16 + n16;               // D col = co
        const float sc = s_sc[co], sh = s_sh[co];
        const float* __restrict__ xb = (cf < 4) ? (ubase + (size_t)co * HW)
                                                : (vbase + (size_t)(co - C1) * HW);
        float* __restrict__ ob = out + ((size_t)n * CC + co) * HW;
#pragma unroll
        for (int pf = 0; pf < 2; ++pf) {
            const int off = (h0 + wid * 2 + pf) * Wd + w0 + kgrp * 4;  // 4 consec w
            f32x4 x = *(const f32x4*)(xb + off);
            f32x4 a = acc[cf][pf];
            f32x4 y;
#pragma unroll
            for (int r = 0; r < 4; ++r)
                y[r] = fmaxf(fmaf(a[r], sc, sh) + x[r], 0.f);
            *(f32x4*)(ob + off) = y;
        }
    }
}

extern "C" void kernel_launch(void* const* d_in, const int* in_sizes, int n_in,
                              void* d_out, int out_size, void* d_ws, size_t ws_size,
                              hipStream_t stream) {
    const float* u     = (const float*)d_in[0];
    const float* v     = (const float*)d_in[1];
    const float* wgt   = (const float*)d_in[2];
    const float* gamma = (const float*)d_in[3];
    const float* beta  = (const float*)d_in[4];
    const float* mean  = (const float*)d_in[5];
    const float* var   = (const float*)d_in[6];
    float* out = (float*)d_out;
    ushort* wf = (ushort*)d_ws;                 // 288 KB of ws for bf16 weight frags

    prep_weights<<<dim3((WFRAGS * 64 + 255) / 256), dim3(256), 0, stream>>>(wgt, wf);
    crossconv_mfma<<<dim3(Wd / 16, Hd / 16, 32), dim3(NTHR), 0, stream>>>(
        u, v, wf, gamma, beta, mean, var, out);
}

// Round 3
// 929.667 us; speedup vs baseline: 1.0827x; 1.0827x over previous
//
#include <hip/hip_runtime.h>
#include <hip/hip_bf16.h>

// CrossConv2d via bf16 MFMA implicit GEMM, co-split waves.
// out[n,co,h,w] = relu( BN(conv3x3(xy)) + xy ),  xy = concat(u[b], v[n])
// One block = one (n, 16x8 tile), 256 threads / 4 waves.
// CO-SPLIT: wave wid owns co group [wid*32, wid*32+32) x ALL 128 tile pixels.
//  -> acc[2][8] = 64 f32/thread; each weight frag feeds 8 MFMAs (8x amortization);
//  -> the 4 waves read DISJOINT weight frags: 73.7 KB/chunk per BLOCK (not per wave).
// ~150 total regs + 256-thr blocks -> 3 blocks/CU (cross-block phase overlap).
// MFMA operand swap: A = pixels (M=w), B = weights (N=co) -> D rows are 4 consecutive w
// -> float4 skip-load + float4 store epilogue.
// Staging: double-buffered LDS, T14 async split (issue loads -> MFMA -> cvt+ds_write).

#define EPS 1e-5f

typedef __attribute__((ext_vector_type(8))) short short8;   // 8 bf16 = 4 VGPRs
typedef __attribute__((ext_vector_type(4))) float f32x4;
typedef __attribute__((ext_vector_type(2))) float f32x2;

constexpr int C1 = 64, CC = 128, Hd = 128, Wd = 128;
constexpr int HW = Hd * Wd;          // 16384
constexpr int TW = 16, TH = 8;       // pixel tile
constexpr int SPW = 18, SPH = 10;    // halo tile dims
constexpr int ROW = 40;              // ushorts per point: 32 ci + 8 pad (80B, 16B-aligned)
constexpr int WFRAGS = 9 * 4 * 8;    // (t, ci-chunk, co-frag)
constexpr int NTHR = 256;
constexpr int UNITS = 16 * SPH * 10; // ci-pair x sph x float2-col units per chunk = 1600
constexpr int NU = (UNITS + NTHR - 1) / NTHR;   // 7

// ---- prep: fp32 OIHW weights -> bf16 B-fragments in ws ----
// frag f = (t*4 + c)*8 + cf ; lane l holds 8 bf16: co = cf*16+(l&15), ci = c*32+(l>>4)*8+j
__global__ void prep_weights(const float* __restrict__ wgt, ushort* __restrict__ wf) {
    int idx = blockIdx.x * 256 + threadIdx.x;
    if (idx >= WFRAGS * 64) return;
    int l  = idx & 63;
    int f  = idx >> 6;
    int cf = f & 7;
    int c  = (f >> 3) & 3;
    int t  = f >> 5;
    int kh = t / 3, kw = t % 3;
    int co  = cf * 16 + (l & 15);
    int cib = c * 32 + (l >> 4) * 8;
    ushort* dst = wf + (size_t)idx * 8;
#pragma unroll
    for (int j = 0; j < 8; ++j) {
        float x = wgt[(((size_t)co * CC + cib + j) * 3 + kh) * 3 + kw];
        __hip_bfloat16 bb = __float2bfloat16(x);
        dst[j] = *(ushort*)&bb;
    }
}

// ---- main: one block = one (n, 16x8 tile); 4 waves, co-split ----
__global__ __launch_bounds__(NTHR, 3)
void crossconv_mfma(const float* __restrict__ u,
                    const float* __restrict__ v,
                    const ushort* __restrict__ wf,
                    const float* __restrict__ gamma,
                    const float* __restrict__ beta,
                    const float* __restrict__ mean,
                    const float* __restrict__ var,
                    float* __restrict__ out) {
    __shared__ alignas(16) ushort in_s[2][SPH * SPW * ROW];   // 2 x 14400 B
    __shared__ float s_sc[CC], s_sh[CC];

    const int tid = threadIdx.x;
    const int w0 = blockIdx.x * TW;
    const int h0 = blockIdx.y * TH;
    const int n  = blockIdx.z;
    const int b  = n >> 3;
    const float* __restrict__ ubase = u + (size_t)b * C1 * HW;
    const float* __restrict__ vbase = v + (size_t)n * C1 * HW;

    if (tid < CC) {
        float sc = gamma[tid] * rsqrtf(var[tid] + EPS);
        s_sc[tid] = sc;
        s_sh[tid] = beta[tid] - mean[tid] * sc;
    }
    // zero both buffers once: OOB/halo slots are identical every chunk and never
    // rewritten, so they stay zero for the whole kernel.
    {
        uint4 z{0u, 0u, 0u, 0u};
        uint4* p = (uint4*)&in_s[0][0];
        for (int i = tid; i < 2 * SPH * SPW * ROW * 2 / 16; i += NTHR) p[i] = z;
    }

    const int l = tid & 63, wid = tid >> 6;   // wave wid -> co group [wid*32, wid*32+32)
    const int n16 = l & 15, kgrp = l >> 4;

    // ---- per-unit staging geometry, hoisted ----
    // unit e: cp = ci-pair (slow), sph = halo row, j = float2 column unit (fast)
    // covers halo cols spw = {2j-1, 2j}  (image w = gw, gw+1 with gw = w0+2j-2)
    int  goff[NU];
    int  sidx[NU];
    uint lm = 0, m0 = 0, m1 = 0;
#pragma unroll
    for (int i = 0; i < NU; ++i) {
        goff[i] = 0; sidx[i] = ROW;
        int e = tid + i * NTHR;
        if (e < UNITS) {
            int cp  = e / 100;              // 100 = SPH * 10 units per ci-pair
            int r   = e - cp * 100;
            int sph = r / 10;
            int j   = r - sph * 10;
            int gh  = h0 + sph - 1;
            int gw  = w0 + 2 * j - 2;       // even -> 8B-aligned float2
            sidx[i] = (sph * SPW + 2 * j) * ROW + 2 * cp;
            if ((unsigned)gh < (unsigned)Hd && (unsigned)gw < (unsigned)(Wd - 1)) {
                goff[i] = 2 * cp * HW + gh * Wd + gw;
                lm |= 1u << i;
                if (j >= 1) m0 |= 1u << i;  // spw = 2j-1 in tile
                if (j <= 8) m1 |= 1u << i;  // spw = 2j   in tile
            }
        }
    }

    f32x4 acc[2][8];                        // [cfl][pf] -- 64 regs
#pragma unroll
    for (int cfl = 0; cfl < 2; ++cfl)
#pragma unroll
        for (int pf = 0; pf < 8; ++pf) acc[cfl][pf] = (f32x4)0.f;

    f32x2 sa[NU], sb[NU];                   // in-flight staging regs (T14)

    auto chunk_src = [&](int c) -> const float* {
        return (c < 2) ? ubase + (size_t)c * 32 * HW
                       : vbase + (size_t)(c - 2) * 32 * HW;
    };
    auto stage_load = [&](const float* __restrict__ src) {
#pragma unroll
        for (int i = 0; i < NU; ++i) {
            sa[i] = f32x2{0.f, 0.f}; sb[i] = f32x2{0.f, 0.f};
            if (lm & (1u << i)) {
                const float* p = src + goff[i];
                sa[i] = *(const f32x2*)p;          // ci = 2cp
                sb[i] = *(const f32x2*)(p + HW);   // ci = 2cp+1
            }
        }
    };
    auto stage_write = [&](int buf) {
        ushort* __restrict__ d = in_s[buf];
#pragma unroll
        for (int i = 0; i < NU; ++i) {
            __hip_bfloat16 ax = __float2bfloat16(sa[i].x);
            __hip_bfloat16 bx = __float2bfloat16(sb[i].x);
            __hip_bfloat16 ay = __float2bfloat16(sa[i].y);
            __hip_bfloat16 by = __float2bfloat16(sb[i].y);
            uint v0 = (uint)*(ushort*)&ax | ((uint)*(ushort*)&bx << 16);
            uint v1 = (uint)*(ushort*)&ay | ((uint)*(ushort*)&by << 16);
            if (m0 & (1u << i)) *(uint*)&d[sidx[i] - ROW] = v0;
            if (m1 & (1u << i)) *(uint*)&d[sidx[i]]       = v1;
        }
    };
    // A = pixels (M=w), B = weights (N=co) -> D: col=co, row=w (float4 epilogue).
    // Wave reads only its 2 co-frags' weights; each frag feeds 8 MFMAs.
    auto compute = [&](int buf, int c) {
        const ushort* __restrict__ bs = in_s[buf];
#pragma unroll
        for (int t = 0; t < 9; ++t) {
            const int kh = t / 3, kw = t % 3;
            const int spw = n16 + kw;
            const short8* __restrict__ wp =
                (const short8*)wf + ((size_t)((t * 4 + c) * 8 + wid * 2)) * 64 + l;
            short8 wf0 = wp[0];
            short8 wf1 = wp[64];
#pragma unroll
            for (int pf = 0; pf < 8; ++pf) {
                short8 p = *(const short8*)&bs[((pf + kh) * SPW + spw) * ROW + kgrp * 8];
                acc[0][pf] = __builtin_amdgcn_mfma_f32_16x16x32_bf16(p, wf0, acc[0][pf], 0, 0, 0);
                acc[1][pf] = __builtin_amdgcn_mfma_f32_16x16x32_bf16(p, wf1, acc[1][pf], 0, 0, 0);
            }
        }
    };

    stage_load(chunk_src(0));
    __syncthreads();               // zero-fill + BN table visible
    stage_write(0);
    __syncthreads();

#pragma unroll
    for (int c = 0; c < 4; ++c) {                  // ci chunks of 32
        if (c < 3) stage_load(chunk_src(c + 1));   // loads fly under MFMA (T14)
        compute(c & 1, c);
        if (c < 3) stage_write((c & 1) ^ 1);
        __syncthreads();           // next buffer ready; current free for c+2
    }

    // ---- epilogue: BN + fp32 skip + ReLU, float4 I/O ----
#pragma unroll
    for (int cfl = 0; cfl < 2; ++cfl) {
        const int co = (wid * 2 + cfl) * 16 + n16;  // D col = co
        const float sc = s_sc[co], sh = s_sh[co];
        const float* __restrict__ xb = (co < C1) ? (ubase + (size_t)co * HW)
                                                 : (vbase + (size_t)(co - C1) * HW);
        float* __restrict__ ob = out + ((size_t)n * CC + co) * HW;
#pragma unroll
        for (int pf = 0; pf < 8; ++pf) {
            const int off = (h0 + pf) * Wd + w0 + kgrp * 4;   // 4 consecutive w
            f32x4 x = *(const f32x4*)(xb + off);
            f32x4 a = acc[cfl][pf];
            f32x4 y;
#pragma unroll
            for (int r = 0; r < 4; ++r)
                y[r] = fmaxf(fmaf(a[r], sc, sh) + x[r], 0.f);
            *(f32x4*)(ob + off) = y;
        }
    }
}

extern "C" void kernel_launch(void* const* d_in, const int* in_sizes, int n_in,
                              void* d_out, int out_size, void* d_ws, size_t ws_size,
                              hipStream_t stream) {
    const float* u     = (const float*)d_in[0];
    const float* v     = (const float*)d_in[1];
    const float* wgt   = (const float*)d_in[2];
    const float* gamma = (const float*)d_in[3];
    const float* beta  = (const float*)d_in[4];
    const float* mean  = (const float*)d_in[5];
    const float* var   = (const float*)d_in[6];
    float* out = (float*)d_out;
    ushort* wf = (ushort*)d_ws;                 // 288 KB of ws for bf16 weight frags

    prep_weights<<<dim3((WFRAGS * 64 + 255) / 256), dim3(256), 0, stream>>>(wgt, wf);
    crossconv_mfma<<<dim3(Wd / TW, Hd / TH, 32), dim3(NTHR), 0, stream>>>(
        u, v, wf, gamma, beta, mean, var, out);
}

// Round 4
// 908.573 us; speedup vs baseline: 1.1078x; 1.0232x over previous
//
#include <hip/hip_runtime.h>
#include <hip/hip_bf16.h>

// CrossConv2d via bf16 MFMA implicit GEMM, co-split waves (round-3 structure, de-spilled).
// out[n,co,h,w] = relu( BN(conv3x3(xy)) + xy ),  xy = concat(u[b], v[n])
// One block = one (n, 16x8 tile), 256 threads / 4 waves.
// CO-SPLIT: wave wid owns co group [wid*32, wid*32+32) x ALL 128 tile pixels.
//  -> acc[2][8] = 64 f32/thread; each weight frag feeds 8 MFMAs;
//  -> 4 waves read DISJOINT weight frags: 73.7 KB/chunk per BLOCK.
// Register discipline (spill fixes vs r3): chunk loop NOT unrolled (one chunk's
// staging live at a time), goff/sidx packed into one u32/unit, lm derived as m0|m1.
// Target: <=170 unified regs -> true 3 blocks/CU under __launch_bounds__(256,3).
// T1 XCD swizzle: consecutive-original blocks (sharing v[n]/u[b] L2 panels) -> same XCD.

#define EPS 1e-5f

typedef __attribute__((ext_vector_type(8))) short short8;   // 8 bf16 = 4 VGPRs
typedef __attribute__((ext_vector_type(4))) float f32x4;
typedef __attribute__((ext_vector_type(2))) float f32x2;

constexpr int C1 = 64, CC = 128, Hd = 128, Wd = 128;
constexpr int HW = Hd * Wd;          // 16384
constexpr int TW = 16, TH = 8;       // pixel tile
constexpr int SPW = 18, SPH = 10;    // halo tile dims
constexpr int ROW = 40;              // ushorts per point: 32 ci + 8 pad (80B; reads 2-way-free)
constexpr int WFRAGS = 9 * 4 * 8;    // (t, ci-chunk, co-frag)
constexpr int NTHR = 256;
constexpr int UNITS = 16 * SPH * 10; // ci-pair x sph x float2-col units per chunk = 1600
constexpr int NU = (UNITS + NTHR - 1) / NTHR;   // 7

// ---- prep: fp32 OIHW weights -> bf16 B-fragments in ws ----
// frag f = (t*4 + c)*8 + cf ; lane l holds 8 bf16: co = cf*16+(l&15), ci = c*32+(l>>4)*8+j
__global__ void prep_weights(const float* __restrict__ wgt, ushort* __restrict__ wf) {
    int idx = blockIdx.x * 256 + threadIdx.x;
    if (idx >= WFRAGS * 64) return;
    int l  = idx & 63;
    int f  = idx >> 6;
    int cf = f & 7;
    int c  = (f >> 3) & 3;
    int t  = f >> 5;
    int kh = t / 3, kw = t % 3;
    int co  = cf * 16 + (l & 15);
    int cib = c * 32 + (l >> 4) * 8;
    ushort* dst = wf + (size_t)idx * 8;
#pragma unroll
    for (int j = 0; j < 8; ++j) {
        float x = wgt[(((size_t)co * CC + cib + j) * 3 + kh) * 3 + kw];
        __hip_bfloat16 bb = __float2bfloat16(x);
        dst[j] = *(ushort*)&bb;
    }
}

// ---- main: one block = one (n, 16x8 tile); 4 waves, co-split ----
__global__ __launch_bounds__(NTHR, 3)
void crossconv_mfma(const float* __restrict__ u,
                    const float* __restrict__ v,
                    const ushort* __restrict__ wf,
                    const float* __restrict__ gamma,
                    const float* __restrict__ beta,
                    const float* __restrict__ mean,
                    const float* __restrict__ var,
                    float* __restrict__ out) {
    __shared__ alignas(16) ushort in_s[2][SPH * SPW * ROW];   // 2 x 14400 B
    __shared__ float s_sc[CC], s_sh[CC];

    const int tid = threadIdx.x;
    // T1: bijective XCD swizzle (4096 % 8 == 0). New-id lin -> original tile id so
    // each XCD's round-robin slots form a CONTIGUOUS original range (shared L2 panels).
    const int lin  = blockIdx.x + 8 * blockIdx.y + 128 * blockIdx.z;
    const int orig = (lin & 7) * 512 + (lin >> 3);
    const int w0 = (orig & 7) * TW;
    const int h0 = ((orig >> 3) & 15) * TH;
    const int n  = orig >> 7;
    const int b  = n >> 3;
    const float* __restrict__ ubase = u + (size_t)b * C1 * HW;
    const float* __restrict__ vbase = v + (size_t)n * C1 * HW;

    if (tid < CC) {
        float sc = gamma[tid] * rsqrtf(var[tid] + EPS);
        s_sc[tid] = sc;
        s_sh[tid] = beta[tid] - mean[tid] * sc;
    }
    // zero both buffers once: OOB/halo slots are identical every chunk and never
    // rewritten, so they stay zero for the whole kernel.
    {
        uint4 z{0u, 0u, 0u, 0u};
        uint4* p = (uint4*)&in_s[0][0];
        for (int i = tid; i < 2 * SPH * SPW * ROW * 2 / 16; i += NTHR) p[i] = z;
    }

    const int l = tid & 63, wid = tid >> 6;   // wave wid -> co group [wid*32, wid*32+32)
    const int n16 = l & 15, kgrp = l >> 4;

    // ---- per-unit staging geometry, hoisted & PACKED: pk = (goff<<13) | sidx ----
    // goff < 2^19 (max ~508K), sidx < 2^13 (max 7190). unit e: cp (slow), sph, j (fast);
    // covers halo cols spw = {2j-1, 2j} (image w = gw, gw+1 with gw = w0+2j-2).
    uint pk[NU];
    uint m0 = 0, m1 = 0;
#pragma unroll
    for (int i = 0; i < NU; ++i) {
        pk[i] = ROW;                        // sidx=ROW, goff=0 (inactive default)
        int e = tid + i * NTHR;
        if (e < UNITS) {
            int cp  = e / 100;              // 100 = SPH * 10 units per ci-pair
            int r   = e - cp * 100;
            int sph = r / 10;
            int j   = r - sph * 10;
            int gh  = h0 + sph - 1;
            int gw  = w0 + 2 * j - 2;       // even -> 8B-aligned float2
            uint sidx = (sph * SPW + 2 * j) * ROW + 2 * cp;
            if ((unsigned)gh < (unsigned)Hd && (unsigned)gw < (unsigned)(Wd - 1)) {
                pk[i] = ((uint)(2 * cp * HW + gh * Wd + gw) << 13) | sidx;
                if (j >= 1) m0 |= 1u << i;  // spw = 2j-1 in tile
                if (j <= 8) m1 |= 1u << i;  // spw = 2j   in tile
            } else {
                pk[i] = sidx;               // masks stay 0 -> never loaded/written
            }
        }
    }

    f32x4 acc[2][8];                        // [cfl][pf] -- 64 regs
#pragma unroll
    for (int cfl = 0; cfl < 2; ++cfl)
#pragma unroll
        for (int pf = 0; pf < 8; ++pf) acc[cfl][pf] = (f32x4)0.f;

    f32x2 sa[NU], sb[NU];                   // in-flight staging regs (T14)

    auto chunk_src = [&](int c) -> const float* {
        return (c < 2) ? ubase + (size_t)c * 32 * HW
                       : vbase + (size_t)(c - 2) * 32 * HW;
    };
    auto stage_load = [&](const float* __restrict__ src) {
        const uint lm = m0 | m1;
#pragma unroll
        for (int i = 0; i < NU; ++i) {
            sa[i] = f32x2{0.f, 0.f}; sb[i] = f32x2{0.f, 0.f};
            if (lm & (1u << i)) {
                const float* p = src + (pk[i] >> 13);
                sa[i] = *(const f32x2*)p;          // ci = 2cp
                sb[i] = *(const f32x2*)(p + HW);   // ci = 2cp+1
            }
        }
    };
    auto stage_write = [&](int buf) {
        ushort* __restrict__ d = in_s[buf];
#pragma unroll
        for (int i = 0; i < NU; ++i) {
            __hip_bfloat16 ax = __float2bfloat16(sa[i].x);
            __hip_bfloat16 bx = __float2bfloat16(sb[i].x);
            __hip_bfloat16 ay = __float2bfloat16(sa[i].y);
            __hip_bfloat16 by = __float2bfloat16(sb[i].y);
            uint v0 = (uint)*(ushort*)&ax | ((uint)*(ushort*)&bx << 16);
            uint v1 = (uint)*(ushort*)&ay | ((uint)*(ushort*)&by << 16);
            int si = (int)(pk[i] & 8191u);
            if (m0 & (1u << i)) *(uint*)&d[si - ROW] = v0;
            if (m1 & (1u << i)) *(uint*)&d[si]       = v1;
        }
    };
    // A = pixels (M=w), B = weights (N=co) -> D: col=co, row=w (float4 epilogue).
    // Wave reads only its 2 co-frags' weights; each frag feeds 8 MFMAs.
    auto compute = [&](int buf, int c) {
        const ushort* __restrict__ bs = in_s[buf];
#pragma unroll
        for (int t = 0; t < 9; ++t) {
            const int kh = t / 3, kw = t % 3;
            const int spw = n16 + kw;
            const short8* __restrict__ wp =
                (const short8*)wf + ((size_t)((t * 4 + c) * 8 + wid * 2)) * 64 + l;
            short8 wf0 = wp[0];
            short8 wf1 = wp[64];
#pragma unroll
            for (int pf = 0; pf < 8; ++pf) {
                short8 p = *(const short8*)&bs[((pf + kh) * SPW + spw) * ROW + kgrp * 8];
                acc[0][pf] = __builtin_amdgcn_mfma_f32_16x16x32_bf16(p, wf0, acc[0][pf], 0, 0, 0);
                acc[1][pf] = __builtin_amdgcn_mfma_f32_16x16x32_bf16(p, wf1, acc[1][pf], 0, 0, 0);
            }
        }
    };

    stage_load(chunk_src(0));
    __syncthreads();               // zero-fill + BN table visible
    stage_write(0);
    __syncthreads();

    for (int c = 0; c < 4; ++c) {                  // ci chunks of 32 -- NOT unrolled
        if (c < 3) stage_load(chunk_src(c + 1));   // loads fly under MFMA (T14)
        compute(c & 1, c);
        if (c < 3) stage_write((c & 1) ^ 1);
        __syncthreads();           // next buffer ready; current free for c+2
    }

    // ---- epilogue: BN + fp32 skip + ReLU, float4 I/O ----
#pragma unroll
    for (int cfl = 0; cfl < 2; ++cfl) {
        const int co = (wid * 2 + cfl) * 16 + n16;  // D col = co
        const float sc = s_sc[co], sh = s_sh[co];
        const float* __restrict__ xb = (co < C1) ? (ubase + (size_t)co * HW)
                                                 : (vbase + (size_t)(co - C1) * HW);
        float* __restrict__ ob = out + ((size_t)n * CC + co) * HW;
#pragma unroll
        for (int pf = 0; pf < 8; ++pf) {
            const int off = (h0 + pf) * Wd + w0 + kgrp * 4;   // 4 consecutive w
            f32x4 x = *(const f32x4*)(xb + off);
            f32x4 a = acc[cfl][pf];
            f32x4 y;
#pragma unroll
            for (int r = 0; r < 4; ++r)
                y[r] = fmaxf(fmaf(a[r], sc, sh) + x[r], 0.f);
            *(f32x4*)(ob + off) = y;
        }
    }
}

extern "C" void kernel_launch(void* const* d_in, const int* in_sizes, int n_in,
                              void* d_out, int out_size, void* d_ws, size_t ws_size,
                              hipStream_t stream) {
    const float* u     = (const float*)d_in[0];
    const float* v     = (const float*)d_in[1];
    const float* wgt   = (const float*)d_in[2];
    const float* gamma = (const float*)d_in[3];
    const float* beta  = (const float*)d_in[4];
    const float* mean  = (const float*)d_in[5];
    const float* var   = (const float*)d_in[6];
    float* out = (float*)d_out;
    ushort* wf = (ushort*)d_ws;                 // 288 KB of ws for bf16 weight frags

    prep_weights<<<dim3((WFRAGS * 64 + 255) / 256), dim3(256), 0, stream>>>(wgt, wf);
    crossconv_mfma<<<dim3(Wd / TW, Hd / TH, 32), dim3(NTHR), 0, stream>>>(
        u, v, wf, gamma, beta, mean, var, out);
}